// Round 3
// baseline (496.432 us; speedup 1.0000x reference)
//
#include <hip/hip_runtime.h>
#include <hip/hip_bf16.h>

#define BT 1024
#define DD 1024
#define HH 2048
#define OO 1024
#define EE 8
#define RMAX 3072   // max padded rows (1024 tokens * 2 assignments, padded per expert)

typedef __bf16 bf16x8 __attribute__((ext_vector_type(8)));
typedef float  f32x4  __attribute__((ext_vector_type(4)));

// async global -> LDS, 16 bytes per lane. LDS dest must be wave-uniform base + lane*16.
__device__ __forceinline__ void cp16(void* l, const void* g) {
    __builtin_amdgcn_global_load_lds(
        (const __attribute__((address_space(1))) void*)g,
        (__attribute__((address_space(3))) void*)l, 16, 0, 0);
}

#define VMW(n)  asm volatile("s_waitcnt vmcnt(" #n ")" ::: "memory")
#define LGKM(n) asm volatile("s_waitcnt lgkmcnt(" #n ")" ::: "memory")
#define SCHED0  __builtin_amdgcn_sched_barrier(0)
#define BAR()   __builtin_amdgcn_s_barrier()

// ---------------- workspace layout (bytes) ----------------
// counts : int[8]              @ 0
// off    : int[9]              @ 256
// tok_e  : int[2048]           @ 1024
// tok_p  : int[2048]           @ 9216
// tok_w  : float[2048]         @ 17408
// elist  : int[8*1024]         @ 25600
// Xg     : bf16[3072*1024]     @ 65536       (end 6356992)
// H1     : bf16[3072*2048]     @ 6356992     (end 18939904)
// H2     : bf16[3072*2048]     @ 18939904    (end 31522816)
// Y      : f32 [3072*1024]     @ 31522816    (end 44105728)
// Wb1    : bf16[8*1024*2048]   @ 44105728    (end 77660160)
// Wb2    : bf16[8*2048*2048]   @ 77660160    (end 144769024)
// Wb3    : bf16[8*2048*1024]   @ 144769024   (end 178323456)   (R0 used 182.5MB -> fits)

// ---------------- router ----------------
__global__ __launch_bounds__(256) void router_kernel(
    const float* __restrict__ x, const float* __restrict__ Wr, const float* __restrict__ br,
    int* __restrict__ counts, int* __restrict__ elist,
    int* __restrict__ tok_e, int* __restrict__ tok_p, float* __restrict__ tok_w)
{
    int b = blockIdx.x;
    int tid = threadIdx.x;
    float acc[EE];
#pragma unroll
    for (int e = 0; e < EE; ++e) acc[e] = 0.f;
    const float* xr = x + (size_t)b * DD;
    for (int d = tid; d < DD; d += 256) {
        float xv = xr[d];
#pragma unroll
        for (int e = 0; e < EE; ++e) acc[e] += xv * Wr[d * EE + e];
    }
    __shared__ float red[4][EE];
    int lane = tid & 63, wv = tid >> 6;
#pragma unroll
    for (int e = 0; e < EE; ++e) {
        float v = acc[e];
#pragma unroll
        for (int o = 32; o > 0; o >>= 1) v += __shfl_down(v, o, 64);
        if (lane == 0) red[wv][e] = v;
    }
    __syncthreads();
    if (tid == 0) {
        float lg[EE];
#pragma unroll
        for (int e = 0; e < EE; ++e) lg[e] = red[0][e] + red[1][e] + red[2][e] + red[3][e] + br[e];
        float mx = lg[0];
#pragma unroll
        for (int e = 1; e < EE; ++e) mx = fmaxf(mx, lg[e]);
        float s = 0.f, p[EE];
#pragma unroll
        for (int e = 0; e < EE; ++e) { p[e] = expf(lg[e] - mx); s += p[e]; }
        float inv = 1.f / s;
#pragma unroll
        for (int e = 0; e < EE; ++e) p[e] *= inv;
        int i0 = 0; float b0 = p[0];
#pragma unroll
        for (int e = 1; e < EE; ++e) if (p[e] > b0) { b0 = p[e]; i0 = e; }
        int i1 = -1; float b1v = -1.f;
#pragma unroll
        for (int e = 0; e < EE; ++e) if (e != i0 && p[e] > b1v) { b1v = p[e]; i1 = e; }
        float s2 = b0 + b1v + 1e-6f;
        float w0 = b0 / s2, w1 = b1v / s2;
        int p0 = atomicAdd(&counts[i0], 1);
        int p1 = atomicAdd(&counts[i1], 1);
        elist[i0 * 1024 + p0] = b;
        elist[i1 * 1024 + p1] = b;
        tok_e[2 * b] = i0; tok_e[2 * b + 1] = i1;
        tok_p[2 * b] = p0; tok_p[2 * b + 1] = p1;
        tok_w[2 * b] = w0; tok_w[2 * b + 1] = w1;
    }
}

// ---------------- padded prefix sum ----------------
__global__ void offsets_kernel(const int* __restrict__ counts, int* __restrict__ off)
{
    if (threadIdx.x == 0 && blockIdx.x == 0) {
        int a = 0;
        for (int e = 0; e < EE; ++e) {
            off[e] = a;
            a += ((counts[e] + 127) >> 7) << 7;
        }
        off[EE] = a;
    }
}

// ---------------- gather x rows -> bf16, pad rows zeroed ----------------
__global__ __launch_bounds__(256) void gather_kernel(
    const float* __restrict__ x, const int* __restrict__ counts, const int* __restrict__ off,
    const int* __restrict__ elist, __bf16* __restrict__ Xg)
{
    int e = blockIdx.y;
    int chunk = blockIdx.x >> 2;
    int rg = blockIdx.x & 3;
    int cnt = counts[e];
    if (chunk * 128 >= cnt) return;
    int base = off[e] + chunk * 128 + rg * 32;
    int tid = threadIdx.x;
    for (int it = 0; it < 32; ++it) {
        int slot = chunk * 128 + rg * 32 + it;
        __bf16 v[4];
        if (slot < cnt) {
            int tok = elist[e * 1024 + slot];
            const float4 f = *(const float4*)(x + (size_t)tok * DD + tid * 4);
            v[0] = (__bf16)f.x; v[1] = (__bf16)f.y; v[2] = (__bf16)f.z; v[3] = (__bf16)f.w;
        } else {
            v[0] = v[1] = v[2] = v[3] = (__bf16)0.f;
        }
        *(uint2*)(Xg + (size_t)(base + it) * DD + tid * 4) = *(uint2*)v;
    }
}

// ---------------- weight prepass: fp32 [K][N] -> bf16 panels [e][nt][ks][64n][64k] ----------------
// Contiguous full-row reads, LDS transpose, contiguous panel writes.
// Panel rows are chunk-XOR-swizzled (LDS chunk c holds data chunk c^(n&7)) so the
// GEMM can DMA panels linearly into LDS and ds_read_b128 conflict-free.
// Block = (ks = 64-k band, e). Slices of 512 n at a time.
template <int K, int N>
__global__ __launch_bounds__(256) void wprep(const float* __restrict__ W, __bf16* __restrict__ Wb)
{
    constexpr int NSL = N / 512;
    int ks = blockIdx.x, e = blockIdx.y;
    int t = threadIdx.x;
    const float* Wp = W + (size_t)e * K * N + (size_t)ks * 64 * N;
    __shared__ __bf16 T[512 * 72];   // [n_slice][72 k-u16] (144B rows: 16B-aligned, bank-spread)

    for (int s = 0; s < NSL; ++s) {
        // stage: [4n x 8k] register tiles; reads are full-row contiguous float4
#pragma unroll
        for (int i = 0; i < 4; ++i) {
            int tau = i * 256 + t;
            int nti = tau & 127;      // 4-n group within slice
            int kt  = tau >> 7;       // 8-k group (0..7)
            float4 f[8];
#pragma unroll
            for (int rr = 0; rr < 8; ++rr)
                f[rr] = *(const float4*)(Wp + (size_t)(kt * 8 + rr) * N + s * 512 + nti * 4);
#pragma unroll
            for (int j = 0; j < 4; ++j) {
                __bf16 t8[8];
#pragma unroll
                for (int rr = 0; rr < 8; ++rr) t8[rr] = (__bf16)((&f[rr].x)[j]);
                *(uint4*)(&T[(nti * 4 + j) * 72 + kt * 8]) = *(uint4*)t8;
            }
        }
        __syncthreads();
        // emit: contiguous 16B panel stores; apply chunk swizzle on the LDS read side
#pragma unroll
        for (int i = 0; i < 16; ++i) {
            int idx = i * 256 + t;
            int ntg = idx >> 9;       // panel within slice (0..7)
            int rem = idx & 511;
            int n = rem >> 3, c = rem & 7;
            uint4 v = *(const uint4*)(&T[(ntg * 64 + n) * 72 + (c ^ (n & 7)) * 8]);
            size_t dst = ((((size_t)e * (N / 64) + (s * 8 + ntg)) * (K / 64) + ks) << 12) + (size_t)rem * 8;
            *(uint4*)(&Wb[dst]) = v;
        }
        __syncthreads();
    }
}

// ---------------- fused full-K MFMA GEMM: Out = act(A * Wb[e] + bias) ----------------
// TM=128, TN=64, BK=64. A and B both staged by linear global_load_lds DMA
// (B panels are pre-transposed+pre-swizzled bf16). 3 LDS buffers each,
// prefetch distance 2, counted vmcnt (VMW(6) keeps next step's 6 DMAs in
// flight across the barrier), one s_barrier per step, setprio around MFMAs.
// Grid: x = nt*8 + e (expert -> XCD pinning), y = mt.
template <int K, int N, bool RELU, bool OUT_BF16>
__global__ __launch_bounds__(256, 2) void gemm_fused(
    const __bf16* __restrict__ A, const __bf16* __restrict__ Wb,
    const float* __restrict__ bias, void* __restrict__ OutV,
    const int* __restrict__ counts, const int* __restrict__ off)
{
    constexpr int NSTEPS = K / 64;

    int e  = blockIdx.x & 7;
    int nt = blockIdx.x >> 3;
    int mt = blockIdx.y;
    int cnt = counts[e];
    if (mt * 128 >= cnt) return;
    int row0 = off[e] + mt * 128;

    const __bf16* Ab = A + (size_t)row0 * K;
    const __bf16* Bp = Wb + ((size_t)e * (N / 64) + nt) * (size_t)(K / 64) * 4096;

    __shared__ __bf16 As[3 * 8192];   // 3 bufs, [128 rows][64 k], swizzled image
    __shared__ __bf16 Bs[3 * 4096];   // 3 bufs, [64 rows][64 k], swizzled image

    int tid = threadIdx.x;
    int wave = tid >> 6, lane = tid & 63;
    int m = lane & 15, q = lane >> 4;
    int wm = (wave >> 1) * 64, wn = (wave & 1) * 32;

    // A-DMA: lane writes LDS chunk (lane&7) of row (i*32 + wave*8 + lane>>3);
    // source chunk pre-XORed so LDS[r][c] holds data chunk c^(r&7).
    int rdma = wave * 8 + (lane >> 3);
    int kxe  = ((lane & 7) ^ (lane >> 3)) * 8;

    f32x4 acc[4][2] = {};

    auto issue = [&](int t) {
        unsigned ab = (unsigned)(t % 3) * 8192;
        unsigned bb = (unsigned)(t % 3) * 4096;
#pragma unroll
        for (int i = 0; i < 4; ++i)
            cp16(&As[ab + i * 2048 + wave * 512 + lane * 8],
                 Ab + (size_t)(i * 32 + rdma) * K + t * 64 + kxe);
#pragma unroll
        for (int r = 0; r < 2; ++r)
            cp16(&Bs[bb + r * 2048 + wave * 512 + lane * 8],
                 Bp + (size_t)t * 4096 + r * 2048 + wave * 512 + lane * 8);
    };

    issue(0);
    issue(1);

    for (int t = 0; t < NSTEPS; ++t) {
        if (t == NSTEPS - 1) { VMW(0); } else { VMW(6); }   // own step's DMAs done; next step's stay in flight
        SCHED0;
        BAR();
        SCHED0;
        if (t + 2 < NSTEPS) issue(t + 2);   // post-barrier: everyone done reading buf (t-1)%3

        unsigned aR = (unsigned)(t % 3) * 8192;
        unsigned bR = (unsigned)(t % 3) * 4096;
        bf16x8 af0[4], bf0[2], af1[4], bf1[2];
#pragma unroll
        for (int i = 0; i < 4; ++i)
            af0[i] = *(bf16x8*)(&As[aR + (wm + i * 16 + m) * 64 + ((q) ^ (m & 7)) * 8]);
#pragma unroll
        for (int j = 0; j < 2; ++j)
            bf0[j] = *(bf16x8*)(&Bs[bR + (wn + j * 16 + m) * 64 + ((q) ^ (m & 7)) * 8]);
        SCHED0;
#pragma unroll
        for (int i = 0; i < 4; ++i)
            af1[i] = *(bf16x8*)(&As[aR + (wm + i * 16 + m) * 64 + ((4 + q) ^ (m & 7)) * 8]);
#pragma unroll
        for (int j = 0; j < 2; ++j)
            bf1[j] = *(bf16x8*)(&Bs[bR + (wn + j * 16 + m) * 64 + ((4 + q) ^ (m & 7)) * 8]);
        LGKM(6); SCHED0;
        __builtin_amdgcn_s_setprio(1);
#pragma unroll
        for (int i = 0; i < 4; ++i)
#pragma unroll
            for (int j = 0; j < 2; ++j)
                acc[i][j] = __builtin_amdgcn_mfma_f32_16x16x32_bf16(af0[i], bf0[j], acc[i][j], 0, 0, 0);
        LGKM(0); SCHED0;
#pragma unroll
        for (int i = 0; i < 4; ++i)
#pragma unroll
            for (int j = 0; j < 2; ++j)
                acc[i][j] = __builtin_amdgcn_mfma_f32_16x16x32_bf16(af1[i], bf1[j], acc[i][j], 0, 0, 0);
        __builtin_amdgcn_s_setprio(0);
    }

    // epilogue: bias (+relu), store. D[row=q*4+r][col=m] per 16x16 subtile.
    const float* bp = bias + (size_t)e * N;
    int colbase = nt * 64 + wn;
#pragma unroll
    for (int j = 0; j < 2; ++j) {
        int col = colbase + j * 16 + m;
        float bv = bp[col];
#pragma unroll
        for (int i = 0; i < 4; ++i) {
            int rbase = row0 + wm + i * 16 + q * 4;
#pragma unroll
            for (int r = 0; r < 4; ++r) {
                float v = acc[i][j][r] + bv;
                if constexpr (RELU) v = fmaxf(v, 0.f);
                if constexpr (OUT_BF16)
                    ((__bf16*)OutV)[(size_t)(rbase + r) * N + col] = (__bf16)v;
                else
                    ((float*)OutV)[(size_t)(rbase + r) * N + col] = v;
            }
        }
    }
}

// ---------------- combine: out[b] = w0 * Y[r0] + w1 * Y[r1] (b3 folded into GEMM3) ----------------
__global__ __launch_bounds__(256) void combine_kernel(
    const float* __restrict__ Y, const int* __restrict__ off,
    const int* __restrict__ tok_e, const int* __restrict__ tok_p,
    const float* __restrict__ tok_w, float* __restrict__ out)
{
    int b = blockIdx.x, t = threadIdx.x;
    int e0 = tok_e[2 * b], e1 = tok_e[2 * b + 1];
    int r0 = off[e0] + tok_p[2 * b];
    int r1 = off[e1] + tok_p[2 * b + 1];
    float w0 = tok_w[2 * b], w1 = tok_w[2 * b + 1];
    int col = t * 4;
    f32x4 s0 = *(const f32x4*)(Y + (size_t)r0 * OO + col);
    f32x4 s1 = *(const f32x4*)(Y + (size_t)r1 * OO + col);
    f32x4 o = s0 * w0 + s1 * w1;
    *(f32x4*)(out + (size_t)b * OO + col) = o;
}

extern "C" void kernel_launch(void* const* d_in, const int* in_sizes, int n_in,
                              void* d_out, int out_size, void* d_ws, size_t ws_size,
                              hipStream_t stream)
{
    (void)in_sizes; (void)n_in; (void)out_size; (void)ws_size;
    const float* x  = (const float*)d_in[0];
    const float* Wr = (const float*)d_in[1];
    const float* br = (const float*)d_in[2];
    const float* W1 = (const float*)d_in[3];
    const float* b1 = (const float*)d_in[4];
    const float* W2 = (const float*)d_in[5];
    const float* b2 = (const float*)d_in[6];
    const float* W3 = (const float*)d_in[7];
    const float* b3 = (const float*)d_in[8];
    float* out = (float*)d_out;

    char* ws = (char*)d_ws;
    int*    counts = (int*)(ws + 0);
    int*    off    = (int*)(ws + 256);
    int*    tok_e  = (int*)(ws + 1024);
    int*    tok_p  = (int*)(ws + 9216);
    float*  tok_w  = (float*)(ws + 17408);
    int*    elist  = (int*)(ws + 25600);
    __bf16* Xg     = (__bf16*)(ws + 65536);
    __bf16* H1     = (__bf16*)(ws + 6356992);
    __bf16* H2     = (__bf16*)(ws + 18939904);
    float*  Y      = (float*)(ws + 31522816);
    __bf16* Wb1    = (__bf16*)(ws + 44105728);
    __bf16* Wb2    = (__bf16*)(ws + 77660160);
    __bf16* Wb3    = (__bf16*)(ws + 144769024);

    hipMemsetAsync(counts, 0, 256, stream);
    router_kernel<<<1024, 256, 0, stream>>>(x, Wr, br, counts, elist, tok_e, tok_p, tok_w);
    offsets_kernel<<<1, 64, 0, stream>>>(counts, off);
    gather_kernel<<<dim3(32, 8), 256, 0, stream>>>(x, counts, off, elist, Xg);

    // weight panelization (contiguous streaming, ~402 MB total)
    wprep<1024, 2048><<<dim3(16, 8), 256, 0, stream>>>(W1, Wb1);
    wprep<2048, 2048><<<dim3(32, 8), 256, 0, stream>>>(W2, Wb2);
    wprep<2048, 1024><<<dim3(32, 8), 256, 0, stream>>>(W3, Wb3);

    gemm_fused<1024, 2048, true,  true ><<<dim3(256, 8), 256, 0, stream>>>(Xg, Wb1, b1, (void*)H1, counts, off);
    gemm_fused<2048, 2048, true,  true ><<<dim3(256, 8), 256, 0, stream>>>(H1, Wb2, b2, (void*)H2, counts, off);
    gemm_fused<2048, 1024, false, false><<<dim3(128, 8), 256, 0, stream>>>(H2, Wb3, b3, (void*)Y,  counts, off);

    combine_kernel<<<1024, 256, 0, stream>>>(Y, off, tok_e, tok_p, tok_w, out);
}

// Round 4
// 495.935 us; speedup vs baseline: 1.0010x; 1.0010x over previous
//
#include <hip/hip_runtime.h>
#include <hip/hip_bf16.h>

#define BT 1024
#define DD 1024
#define HH 2048
#define OO 1024
#define EE 8
#define RMAX 3072   // max padded rows (1024 tokens * 2 assignments, padded per expert)

typedef __bf16 bf16x8 __attribute__((ext_vector_type(8)));
typedef float  f32x4  __attribute__((ext_vector_type(4)));

// async global -> LDS, 16 bytes per lane. LDS dest must be wave-uniform base + lane*16.
__device__ __forceinline__ void cp16(void* l, const void* g) {
    __builtin_amdgcn_global_load_lds(
        (const __attribute__((address_space(1))) void*)g,
        (__attribute__((address_space(3))) void*)l, 16, 0, 0);
}

#define VMW(n)  asm volatile("s_waitcnt vmcnt(" #n ")" ::: "memory")
#define LGKM(n) asm volatile("s_waitcnt lgkmcnt(" #n ")" ::: "memory")
#define SCHED0  __builtin_amdgcn_sched_barrier(0)
#define BAR()   __builtin_amdgcn_s_barrier()

// ---------------- workspace layout (bytes) ----------------
// counts : int[8]              @ 0
// off    : int[9]              @ 256
// tok_e  : int[2048]           @ 1024
// tok_p  : int[2048]           @ 9216
// tok_w  : float[2048]         @ 17408
// elist  : int[8*1024]         @ 25600
// Xg     : bf16[3072*1024]     @ 65536       (end 6356992)
// H1     : bf16[3072*2048]     @ 6356992     (end 18939904)
// H2     : bf16[3072*2048]     @ 18939904    (end 31522816)
// Y      : f32 [3072*1024]     @ 31522816    (end 44105728)
// Wb1    : bf16[8*1024*2048]   @ 44105728    (end 77660160)
// Wb2    : bf16[8*2048*2048]   @ 77660160    (end 144769024)
// Wb3    : bf16[8*2048*1024]   @ 144769024   (end 178323456)

// ---------------- router ----------------
__global__ __launch_bounds__(256) void router_kernel(
    const float* __restrict__ x, const float* __restrict__ Wr, const float* __restrict__ br,
    int* __restrict__ counts, int* __restrict__ elist,
    int* __restrict__ tok_e, int* __restrict__ tok_p, float* __restrict__ tok_w)
{
    int b = blockIdx.x;
    int tid = threadIdx.x;
    float acc[EE];
#pragma unroll
    for (int e = 0; e < EE; ++e) acc[e] = 0.f;
    const float* xr = x + (size_t)b * DD;
    for (int d = tid; d < DD; d += 256) {
        float xv = xr[d];
#pragma unroll
        for (int e = 0; e < EE; ++e) acc[e] += xv * Wr[d * EE + e];
    }
    __shared__ float red[4][EE];
    int lane = tid & 63, wv = tid >> 6;
#pragma unroll
    for (int e = 0; e < EE; ++e) {
        float v = acc[e];
#pragma unroll
        for (int o = 32; o > 0; o >>= 1) v += __shfl_down(v, o, 64);
        if (lane == 0) red[wv][e] = v;
    }
    __syncthreads();
    if (tid == 0) {
        float lg[EE];
#pragma unroll
        for (int e = 0; e < EE; ++e) lg[e] = red[0][e] + red[1][e] + red[2][e] + red[3][e] + br[e];
        float mx = lg[0];
#pragma unroll
        for (int e = 1; e < EE; ++e) mx = fmaxf(mx, lg[e]);
        float s = 0.f, p[EE];
#pragma unroll
        for (int e = 0; e < EE; ++e) { p[e] = expf(lg[e] - mx); s += p[e]; }
        float inv = 1.f / s;
#pragma unroll
        for (int e = 0; e < EE; ++e) p[e] *= inv;
        int i0 = 0; float b0 = p[0];
#pragma unroll
        for (int e = 1; e < EE; ++e) if (p[e] > b0) { b0 = p[e]; i0 = e; }
        int i1 = -1; float b1v = -1.f;
#pragma unroll
        for (int e = 0; e < EE; ++e) if (e != i0 && p[e] > b1v) { b1v = p[e]; i1 = e; }
        float s2 = b0 + b1v + 1e-6f;
        float w0 = b0 / s2, w1 = b1v / s2;
        int p0 = atomicAdd(&counts[i0], 1);
        int p1 = atomicAdd(&counts[i1], 1);
        elist[i0 * 1024 + p0] = b;
        elist[i1 * 1024 + p1] = b;
        tok_e[2 * b] = i0; tok_e[2 * b + 1] = i1;
        tok_p[2 * b] = p0; tok_p[2 * b + 1] = p1;
        tok_w[2 * b] = w0; tok_w[2 * b + 1] = w1;
    }
}

// ---------------- padded prefix sum ----------------
__global__ void offsets_kernel(const int* __restrict__ counts, int* __restrict__ off)
{
    if (threadIdx.x == 0 && blockIdx.x == 0) {
        int a = 0;
        for (int e = 0; e < EE; ++e) {
            off[e] = a;
            a += ((counts[e] + 127) >> 7) << 7;
        }
        off[EE] = a;
    }
}

// ---------------- gather x rows -> bf16, pad rows zeroed ----------------
__global__ __launch_bounds__(256) void gather_kernel(
    const float* __restrict__ x, const int* __restrict__ counts, const int* __restrict__ off,
    const int* __restrict__ elist, __bf16* __restrict__ Xg)
{
    int e = blockIdx.y;
    int chunk = blockIdx.x >> 2;
    int rg = blockIdx.x & 3;
    int cnt = counts[e];
    if (chunk * 128 >= cnt) return;
    int base = off[e] + chunk * 128 + rg * 32;
    int tid = threadIdx.x;
    for (int it = 0; it < 32; ++it) {
        int slot = chunk * 128 + rg * 32 + it;
        __bf16 v[4];
        if (slot < cnt) {
            int tok = elist[e * 1024 + slot];
            const float4 f = *(const float4*)(x + (size_t)tok * DD + tid * 4);
            v[0] = (__bf16)f.x; v[1] = (__bf16)f.y; v[2] = (__bf16)f.z; v[3] = (__bf16)f.w;
        } else {
            v[0] = v[1] = v[2] = v[3] = (__bf16)0.f;
        }
        *(uint2*)(Xg + (size_t)(base + it) * DD + tid * 4) = *(uint2*)v;
    }
}

// ---------------- weight prepass: fp32 [K][N] -> bf16 panels ----------------
// Panel unit (per e, nt, 32-k band): [64 n][4 slots of 16B], 4KB contiguous.
// Slot c of row n holds k-chunk q = c ^ ((n>>1)&3) (the GEMM's LDS XOR pre-baked),
// so the GEMM DMAs panels LINEARLY into LDS and reads ds_read_b128 alias-free.
// READ SIDE IS FULLY CONTIGUOUS: block (kb,e) reads 32 complete 8KB rows
// sequentially (256KB). No strided global touches anywhere (fix for the
// ~1.5 TB/s strided-W wall seen in R0-R3).
template <int K, int N>
__global__ __launch_bounds__(512, 1) void wprep(const float* __restrict__ W, __bf16* __restrict__ Wb)
{
    int kb = blockIdx.x, e = blockIdx.y;
    int t = threadIdx.x;
    const float* Wp = W + (size_t)e * K * N + (size_t)kb * 32 * N;
    __shared__ __bf16 T[32 * N];     // [32 k][N n] bf16 row-major

    // read: 32 full rows, fully coalesced float4
#pragma unroll
    for (int j = 0; j < N / 64; ++j) {
        int g = j * 512 + t;                 // over 32*N/4 float4s
        int row = g >> (N == 2048 ? 9 : 8);
        int n4 = g & (N / 4 - 1);
        float4 f = *(const float4*)(Wp + (size_t)row * N + n4 * 4);
        __bf16 v[4] = { (__bf16)f.x, (__bf16)f.y, (__bf16)f.z, (__bf16)f.w };
        *(uint2*)(&T[row * N + n4 * 4]) = *(uint2*)v;
    }
    __syncthreads();

    // emit: (N/64) panels x 256 chunks of 16B, fully contiguous 16B stores
    __bf16* Wbp = Wb + (((size_t)e * (N / 64)) * (K / 32) + kb) * 2048;
#pragma unroll
    for (int rnd = 0; rnd < (N / 64) * 256 / 512; ++rnd) {
        int c = rnd * 512 + t;
        int nt = c >> 8;                     // panel index
        int cid = c & 255;
        int n = cid >> 2, slot = cid & 3;
        int q = slot ^ ((n >> 1) & 3);       // k-chunk stored in this slot
        __bf16 v[8];
#pragma unroll
        for (int kk = 0; kk < 8; ++kk)
            v[kk] = T[(q * 8 + kk) * N + nt * 64 + n];
        __bf16* dst = Wbp + (size_t)nt * (K / 32) * 2048 + n * 32 + slot * 8;
        *(uint4*)dst = *(uint4*)v;
    }
}

// ---------------- fused full-K MFMA GEMM: Out = act(A * Wb[e] + bias) ----------------
// TM=128, TN=64, BK=32. A: row-major [row][32k] LDS image with slot-XOR
// ((row>>1)&3) baked via pre-swizzled DMA source; B: linear DMA of pre-baked
// panels. 4 LDS buffers (48KB -> 3 blocks/CU), prefetch distance 3, counted
// vmcnt (VMW(6) keeps 2 future steps' 3-cp16 groups in flight across the
// barrier), ONE s_barrier per step, setprio around MFMAs.
// Grid: x = nt*8 + e (expert -> XCD pinning), y = mt.
template <int K, int N, bool RELU, bool OUT_BF16>
__global__ __launch_bounds__(256, 3) void gemm_fused(
    const __bf16* __restrict__ A, const __bf16* __restrict__ Wb,
    const float* __restrict__ bias, void* __restrict__ OutV,
    const int* __restrict__ counts, const int* __restrict__ off)
{
    constexpr int NSTEPS = K / 32;

    int e  = blockIdx.x & 7;
    int nt = blockIdx.x >> 3;
    int mt = blockIdx.y;
    int cnt = counts[e];
    if (mt * 128 >= cnt) return;
    int row0 = off[e] + mt * 128;

    const __bf16* Ab = A + (size_t)row0 * K;
    const __bf16* Bp = Wb + ((size_t)e * (N / 64) + nt) * (size_t)(K / 32) * 2048;

    __shared__ __bf16 As[4 * 4096];   // 4 bufs, [128 rows][32 k] (64B rows, slot-XOR image)
    __shared__ __bf16 Bs[4 * 2048];   // 4 bufs, [64 n][32 k]   (64B rows, slot-XOR image)

    int tid = threadIdx.x;
    int wave = tid >> 6, lane = tid & 63;
    int m = lane & 15, q = lane >> 4;
    int wm = (wave >> 1) * 64, wn = (wave & 1) * 32;

    // A-DMA: cp16 writes rows span..span+15 linearly (lane>>2 = row, lane&3 = slot).
    // Source k-chunk = slot ^ ((row>>1)&3) = (lane&3) ^ ((lane>>3)&3)  [span%16==0].
    int adr = lane >> 2;
    int asrc = ((lane & 3) ^ ((lane >> 3) & 3)) * 8;

    f32x4 acc[4][2] = {};

    auto issue = [&](int t) {
        unsigned ab = (unsigned)(t & 3) * 4096;
        unsigned bb = (unsigned)(t & 3) * 2048;
        int s0 = wave * 32, s1 = wave * 32 + 16;
        cp16(&As[ab + wave * 1024 + lane * 8],
             Ab + (size_t)(s0 + adr) * K + t * 32 + asrc);
        cp16(&As[ab + wave * 1024 + 512 + lane * 8],
             Ab + (size_t)(s1 + adr) * K + t * 32 + asrc);
        cp16(&Bs[bb + wave * 512 + lane * 8],
             Bp + (size_t)t * 2048 + wave * 512 + lane * 8);
    };

    issue(0); issue(1); issue(2);

    for (int t = 0; t < NSTEPS; ++t) {
        if (t + 3 < NSTEPS) { VMW(6); } else { VMW(0); }   // own step done; future steps stay in flight
        SCHED0;
        BAR();
        SCHED0;
        if (t + 3 < NSTEPS) issue(t + 3);   // post-barrier: buf (t-1)&3 is free

        unsigned aR = (unsigned)(t & 3) * 4096;
        unsigned bR = (unsigned)(t & 3) * 2048;
        bf16x8 af[4], bfr[2];
#pragma unroll
        for (int i = 0; i < 4; ++i) {
            int row = wm + i * 16 + m;
            af[i] = *(bf16x8*)(&As[aR + row * 32 + (q ^ ((row >> 1) & 3)) * 8]);
        }
#pragma unroll
        for (int j = 0; j < 2; ++j) {
            int n = wn + j * 16 + m;
            bfr[j] = *(bf16x8*)(&Bs[bR + n * 32 + (q ^ ((n >> 1) & 3)) * 8]);
        }
        LGKM(0); SCHED0;
        __builtin_amdgcn_s_setprio(1);
#pragma unroll
        for (int i = 0; i < 4; ++i)
#pragma unroll
            for (int j = 0; j < 2; ++j)
                acc[i][j] = __builtin_amdgcn_mfma_f32_16x16x32_bf16(af[i], bfr[j], acc[i][j], 0, 0, 0);
        __builtin_amdgcn_s_setprio(0);
    }

    // epilogue: bias (+relu), store. D[row=q*4+r][col=m] per 16x16 subtile.
    const float* bp = bias + (size_t)e * N;
    int colbase = nt * 64 + wn;
#pragma unroll
    for (int j = 0; j < 2; ++j) {
        int col = colbase + j * 16 + m;
        float bv = bp[col];
#pragma unroll
        for (int i = 0; i < 4; ++i) {
            int rbase = row0 + wm + i * 16 + q * 4;
#pragma unroll
            for (int r = 0; r < 4; ++r) {
                float v = acc[i][j][r] + bv;
                if constexpr (RELU) v = fmaxf(v, 0.f);
                if constexpr (OUT_BF16)
                    ((__bf16*)OutV)[(size_t)(rbase + r) * N + col] = (__bf16)v;
                else
                    ((float*)OutV)[(size_t)(rbase + r) * N + col] = v;
            }
        }
    }
}

// ---------------- combine: out[b] = w0 * Y[r0] + w1 * Y[r1] (b3 folded into GEMM3) ----------------
__global__ __launch_bounds__(256) void combine_kernel(
    const float* __restrict__ Y, const int* __restrict__ off,
    const int* __restrict__ tok_e, const int* __restrict__ tok_p,
    const float* __restrict__ tok_w, float* __restrict__ out)
{
    int b = blockIdx.x, t = threadIdx.x;
    int e0 = tok_e[2 * b], e1 = tok_e[2 * b + 1];
    int r0 = off[e0] + tok_p[2 * b];
    int r1 = off[e1] + tok_p[2 * b + 1];
    float w0 = tok_w[2 * b], w1 = tok_w[2 * b + 1];
    int col = t * 4;
    f32x4 s0 = *(const f32x4*)(Y + (size_t)r0 * OO + col);
    f32x4 s1 = *(const f32x4*)(Y + (size_t)r1 * OO + col);
    f32x4 o = s0 * w0 + s1 * w1;
    *(f32x4*)(out + (size_t)b * OO + col) = o;
}

extern "C" void kernel_launch(void* const* d_in, const int* in_sizes, int n_in,
                              void* d_out, int out_size, void* d_ws, size_t ws_size,
                              hipStream_t stream)
{
    (void)in_sizes; (void)n_in; (void)out_size; (void)ws_size;
    const float* x  = (const float*)d_in[0];
    const float* Wr = (const float*)d_in[1];
    const float* br = (const float*)d_in[2];
    const float* W1 = (const float*)d_in[3];
    const float* b1 = (const float*)d_in[4];
    const float* W2 = (const float*)d_in[5];
    const float* b2 = (const float*)d_in[6];
    const float* W3 = (const float*)d_in[7];
    const float* b3 = (const float*)d_in[8];
    float* out = (float*)d_out;

    char* ws = (char*)d_ws;
    int*    counts = (int*)(ws + 0);
    int*    off    = (int*)(ws + 256);
    int*    tok_e  = (int*)(ws + 1024);
    int*    tok_p  = (int*)(ws + 9216);
    float*  tok_w  = (float*)(ws + 17408);
    int*    elist  = (int*)(ws + 25600);
    __bf16* Xg     = (__bf16*)(ws + 65536);
    __bf16* H1     = (__bf16*)(ws + 6356992);
    __bf16* H2     = (__bf16*)(ws + 18939904);
    float*  Y      = (float*)(ws + 31522816);
    __bf16* Wb1    = (__bf16*)(ws + 44105728);
    __bf16* Wb2    = (__bf16*)(ws + 77660160);
    __bf16* Wb3    = (__bf16*)(ws + 144769024);

    hipMemsetAsync(counts, 0, 256, stream);
    router_kernel<<<1024, 256, 0, stream>>>(x, Wr, br, counts, elist, tok_e, tok_p, tok_w);
    offsets_kernel<<<1, 64, 0, stream>>>(counts, off);
    gather_kernel<<<dim3(32, 8), 256, 0, stream>>>(x, counts, off, elist, Xg);

    // weight panelization: fully contiguous reads (32 complete rows per block)
    wprep<1024, 2048><<<dim3(32, 8), 512, 0, stream>>>(W1, Wb1);
    wprep<2048, 2048><<<dim3(64, 8), 512, 0, stream>>>(W2, Wb2);
    wprep<2048, 1024><<<dim3(64, 8), 512, 0, stream>>>(W3, Wb3);

    gemm_fused<1024, 2048, true,  true ><<<dim3(256, 8), 256, 0, stream>>>(Xg, Wb1, b1, (void*)H1, counts, off);
    gemm_fused<2048, 2048, true,  true ><<<dim3(256, 8), 256, 0, stream>>>(H1, Wb2, b2, (void*)H2, counts, off);
    gemm_fused<2048, 1024, false, false><<<dim3(128, 8), 256, 0, stream>>>(H2, Wb3, b3, (void*)Y,  counts, off);

    combine_kernel<<<1024, 256, 0, stream>>>(Y, off, tok_e, tok_p, tok_w, out);
}

// Round 5
// 420.707 us; speedup vs baseline: 1.1800x; 1.1788x over previous
//
#include <hip/hip_runtime.h>
#include <hip/hip_bf16.h>

#define BT 1024
#define DD 1024
#define HH 2048
#define OO 1024
#define EE 8
#define RMAX 3072   // max padded rows (1024 tokens * 2 assignments, padded per expert)

typedef __bf16 bf16x8 __attribute__((ext_vector_type(8)));
typedef float  f32x4  __attribute__((ext_vector_type(4)));

// async global -> LDS, 16 bytes per lane. LDS dest must be wave-uniform base + lane*16.
__device__ __forceinline__ void cp16(void* l, const void* g) {
    __builtin_amdgcn_global_load_lds(
        (const __attribute__((address_space(1))) void*)g,
        (__attribute__((address_space(3))) void*)l, 16, 0, 0);
}

#define VMW(n)  asm volatile("s_waitcnt vmcnt(" #n ")" ::: "memory")
#define LGKM(n) asm volatile("s_waitcnt lgkmcnt(" #n ")" ::: "memory")
#define SCHED0  __builtin_amdgcn_sched_barrier(0)
#define BAR()   __builtin_amdgcn_s_barrier()

// ---------------- workspace layout (bytes) ----------------
// counts : int[8]              @ 0
// off    : int[9]              @ 256
// tok_e  : int[2048]           @ 1024
// tok_p  : int[2048]           @ 9216
// tok_w  : float[2048]         @ 17408
// elist  : int[8*1024]         @ 25600
// Xg     : bf16[3072*1024]     @ 65536       (end 6356992)
// H1     : bf16[3072*2048]     @ 6356992     (end 18939904)
// H2     : bf16[3072*2048]     @ 18939904    (end 31522816)
// Y      : f32 [3072*1024]     @ 31522816    (end 44105728)

// ---------------- router ----------------
__global__ __launch_bounds__(256) void router_kernel(
    const float* __restrict__ x, const float* __restrict__ Wr, const float* __restrict__ br,
    int* __restrict__ counts, int* __restrict__ elist,
    int* __restrict__ tok_e, int* __restrict__ tok_p, float* __restrict__ tok_w)
{
    int b = blockIdx.x;
    int tid = threadIdx.x;
    float acc[EE];
#pragma unroll
    for (int e = 0; e < EE; ++e) acc[e] = 0.f;
    const float* xr = x + (size_t)b * DD;
    for (int d = tid; d < DD; d += 256) {
        float xv = xr[d];
#pragma unroll
        for (int e = 0; e < EE; ++e) acc[e] += xv * Wr[d * EE + e];
    }
    __shared__ float red[4][EE];
    int lane = tid & 63, wv = tid >> 6;
#pragma unroll
    for (int e = 0; e < EE; ++e) {
        float v = acc[e];
#pragma unroll
        for (int o = 32; o > 0; o >>= 1) v += __shfl_down(v, o, 64);
        if (lane == 0) red[wv][e] = v;
    }
    __syncthreads();
    if (tid == 0) {
        float lg[EE];
#pragma unroll
        for (int e = 0; e < EE; ++e) lg[e] = red[0][e] + red[1][e] + red[2][e] + red[3][e] + br[e];
        float mx = lg[0];
#pragma unroll
        for (int e = 1; e < EE; ++e) mx = fmaxf(mx, lg[e]);
        float s = 0.f, p[EE];
#pragma unroll
        for (int e = 0; e < EE; ++e) { p[e] = expf(lg[e] - mx); s += p[e]; }
        float inv = 1.f / s;
#pragma unroll
        for (int e = 0; e < EE; ++e) p[e] *= inv;
        int i0 = 0; float b0 = p[0];
#pragma unroll
        for (int e = 1; e < EE; ++e) if (p[e] > b0) { b0 = p[e]; i0 = e; }
        int i1 = -1; float b1v = -1.f;
#pragma unroll
        for (int e = 0; e < EE; ++e) if (e != i0 && p[e] > b1v) { b1v = p[e]; i1 = e; }
        float s2 = b0 + b1v + 1e-6f;
        float w0 = b0 / s2, w1 = b1v / s2;
        int p0 = atomicAdd(&counts[i0], 1);
        int p1 = atomicAdd(&counts[i1], 1);
        elist[i0 * 1024 + p0] = b;
        elist[i1 * 1024 + p1] = b;
        tok_e[2 * b] = i0; tok_e[2 * b + 1] = i1;
        tok_p[2 * b] = p0; tok_p[2 * b + 1] = p1;
        tok_w[2 * b] = w0; tok_w[2 * b + 1] = w1;
    }
}

// ---------------- padded prefix sum ----------------
__global__ void offsets_kernel(const int* __restrict__ counts, int* __restrict__ off)
{
    if (threadIdx.x == 0 && blockIdx.x == 0) {
        int a = 0;
        for (int e = 0; e < EE; ++e) {
            off[e] = a;
            a += ((counts[e] + 127) >> 7) << 7;
        }
        off[EE] = a;
    }
}

// ---------------- gather x rows -> bf16, pad rows zeroed ----------------
__global__ __launch_bounds__(256) void gather_kernel(
    const float* __restrict__ x, const int* __restrict__ counts, const int* __restrict__ off,
    const int* __restrict__ elist, __bf16* __restrict__ Xg)
{
    int e = blockIdx.y;
    int chunk = blockIdx.x >> 2;
    int rg = blockIdx.x & 3;
    int cnt = counts[e];
    if (chunk * 128 >= cnt) return;
    int base = off[e] + chunk * 128 + rg * 32;
    int tid = threadIdx.x;
    for (int it = 0; it < 32; ++it) {
        int slot = chunk * 128 + rg * 32 + it;
        __bf16 v[4];
        if (slot < cnt) {
            int tok = elist[e * 1024 + slot];
            const float4 f = *(const float4*)(x + (size_t)tok * DD + tid * 4);
            v[0] = (__bf16)f.x; v[1] = (__bf16)f.y; v[2] = (__bf16)f.z; v[3] = (__bf16)f.w;
        } else {
            v[0] = v[1] = v[2] = v[3] = (__bf16)0.f;
        }
        *(uint2*)(Xg + (size_t)(base + it) * DD + tid * 4) = *(uint2*)v;
    }
}

// ---------------- fused full-K MFMA GEMM: Out = act(A * W[e] + bias) ----------------
// TM=128, TN=64, BK=32. Direct fp32 W reads (no prepass).
//  - A: global_load_lds into 4 LDS bufs, slot-XOR image, issue distance 3,
//    retired at distance ~2 (audited ledger below).
//  - B: reg-staged fp32->bf16, parity double reg-set + parity LDS double buffer,
//    issue distance 2, retired at distance ~1.7 steps.
//  - ONE raw s_barrier per step. Steady-state VMW(10) retires exactly
//    {A(t+2) [2 cp16], B(t+1) [8 dwords]}; never drains the newer loads.
//    Queue at VMW point (issue order): [A(t+2),B(t+1),A(t+3),B(t+2)] = 20.
//  - Tail: VMW(8) at t==NS-3 (A-issues stopped), VMW(0) at t==NS-2.
// Grid: x = nt*8 + e (expert -> XCD pinning), y = mt.
template <int K, int N, bool RELU, bool OUT_BF16>
__global__ __launch_bounds__(256, 2) void gemm_fused(
    const __bf16* __restrict__ A, const float* __restrict__ W,
    const float* __restrict__ bias, void* __restrict__ OutV,
    const int* __restrict__ counts, const int* __restrict__ off)
{
    constexpr int NSTEPS = K / 32;

    int e  = blockIdx.x & 7;
    int nt = blockIdx.x >> 3;
    int mt = blockIdx.y;
    int cnt = counts[e];
    if (mt * 128 >= cnt) return;
    int row0 = off[e] + mt * 128;

    const __bf16* Ab = A + (size_t)row0 * K;
    const float*  Wp = W + (size_t)e * K * N + nt * 64;

    __shared__ __bf16 As[4 * 4096];   // 4 bufs, [128 rows][32 k] (64B rows, slot-XOR image)
    __shared__ __bf16 Bs[2 * 2048];   // 2 bufs (parity), [64 n][32 k] (64B rows, slot-XOR image)

    int tid = threadIdx.x;
    int wave = tid >> 6, lane = tid & 63;
    int m = lane & 15, q = lane >> 4;
    int wm = (wave >> 1) * 64, wn = (wave & 1) * 32;

    // A-DMA: cp16 writes 16 rows linearly (lane>>2 = row-in-16, lane&3 = slot).
    // Source k-chunk = slot ^ ((row>>1)&3) so LDS holds the slot-XOR image.
    int adr  = lane >> 2;
    int asrc = ((lane & 3) ^ ((lane >> 3) & 3)) * 8;

    // B-stage: thread owns column bn, 8 consecutive k's at bkc; one 16B LDS
    // store per step at the slot-XOR position.
    int bn = tid & 63;
    int bkc = (tid >> 6) * 8;
    int bslot = (bkc >> 3) ^ ((bn >> 1) & 3);

    float bA[8], bB[8];
    f32x4 acc[4][2] = {};

    auto issueA = [&](int t) {
        unsigned ab = (unsigned)(t & 3) * 4096;
        cp16(&As[ab + wave * 1024 + lane * 8],
             Ab + (size_t)(wave * 32 + adr) * K + t * 32 + asrc);
        cp16(&As[ab + wave * 1024 + 512 + lane * 8],
             Ab + (size_t)(wave * 32 + 16 + adr) * K + t * 32 + asrc);
    };
    auto loadB = [&](int t, float (&br_)[8]) {
        const float* p = Wp + (size_t)(t * 32 + bkc) * N + bn;   // 256B contiguous per wave per g
#pragma unroll
        for (int g = 0; g < 8; ++g) br_[g] = p[(size_t)g * N];
    };
    auto writeB = [&](int tw, float (&br_)[8]) {
        __attribute__((aligned(16))) __bf16 t8[8];
#pragma unroll
        for (int g = 0; g < 8; ++g) t8[g] = (__bf16)br_[g];
        *(uint4*)(&Bs[(unsigned)(tw & 1) * 2048 + bn * 32 + bslot * 8]) = *(uint4*)t8;
    };

    auto compute = [&](int t) {
        unsigned aR = (unsigned)(t & 3) * 4096;
        unsigned bR = (unsigned)(t & 1) * 2048;
        bf16x8 af[4], bfr[2];
#pragma unroll
        for (int i = 0; i < 4; ++i) {
            int row = wm + i * 16 + m;
            af[i] = *(bf16x8*)(&As[aR + row * 32 + (q ^ ((row >> 1) & 3)) * 8]);
        }
#pragma unroll
        for (int j = 0; j < 2; ++j) {
            int n = wn + j * 16 + m;
            bfr[j] = *(bf16x8*)(&Bs[bR + n * 32 + (q ^ ((n >> 1) & 3)) * 8]);
        }
        LGKM(0); SCHED0;
        __builtin_amdgcn_s_setprio(1);
#pragma unroll
        for (int i = 0; i < 4; ++i)
#pragma unroll
            for (int j = 0; j < 2; ++j)
                acc[i][j] = __builtin_amdgcn_mfma_f32_16x16x32_bf16(af[i], bfr[j], acc[i][j], 0, 0, 0);
        __builtin_amdgcn_s_setprio(0);
    };

    // prologue (queue after: [A1,B1,A2] = 12)
    issueA(0);
    loadB(0, bA);
    issueA(1);
    loadB(1, bB);
    issueA(2);
    VMW(12); SCHED0;            // retire A0,B0
    writeB(0, bA);
    LGKM(0);

    for (int t = 0; t < NSTEPS; t += 2) {
        // ---- even step t: read Bs[0]; write B(t+1) from bB; load B(t+2)->bA ----
        BAR(); SCHED0;
        if (t + 3 < NSTEPS) issueA(t + 3);
        if (t + 2 < NSTEPS) loadB(t + 2, bA);
        SCHED0;
        compute(t);
        if (t < NSTEPS - 3)      { VMW(10); }   // retire A(t+2),B(t+1); keep A(t+3),B(t+2)
        else                     { VMW(0);  }   // t==NS-2: only B(t+1) left
        SCHED0;
        writeB(t + 1, bB);
        LGKM(0);

        // ---- odd step t+1: read Bs[1]; write B(t+2) from bA; load B(t+3)->bB ----
        BAR(); SCHED0;
        if (t + 4 < NSTEPS) issueA(t + 4);
        if (t + 3 < NSTEPS) loadB(t + 3, bB);
        SCHED0;
        compute(t + 1);
        if (t + 1 < NSTEPS - 1) {
            if (t + 1 < NSTEPS - 3)       { VMW(10); }
            else if (t + 1 == NSTEPS - 3) { VMW(8);  }  // A-issues stopped; keep B(t+3)
            else                          { VMW(0);  }
            SCHED0;
            writeB(t + 2, bA);
            LGKM(0);
        }
    }

    // epilogue: bias (+relu), store. D[row=q*4+r][col=m] per 16x16 subtile.
    const float* bp = bias + (size_t)e * N;
    int colbase = nt * 64 + wn;
#pragma unroll
    for (int j = 0; j < 2; ++j) {
        int col = colbase + j * 16 + m;
        float bv = bp[col];
#pragma unroll
        for (int i = 0; i < 4; ++i) {
            int rbase = row0 + wm + i * 16 + q * 4;
#pragma unroll
            for (int r = 0; r < 4; ++r) {
                float v = acc[i][j][r] + bv;
                if constexpr (RELU) v = fmaxf(v, 0.f);
                if constexpr (OUT_BF16)
                    ((__bf16*)OutV)[(size_t)(rbase + r) * N + col] = (__bf16)v;
                else
                    ((float*)OutV)[(size_t)(rbase + r) * N + col] = v;
            }
        }
    }
}

// ---------------- combine: out[b] = w0 * Y[r0] + w1 * Y[r1] (b3 folded into GEMM3) ----------------
__global__ __launch_bounds__(256) void combine_kernel(
    const float* __restrict__ Y, const int* __restrict__ off,
    const int* __restrict__ tok_e, const int* __restrict__ tok_p,
    const float* __restrict__ tok_w, float* __restrict__ out)
{
    int b = blockIdx.x, t = threadIdx.x;
    int e0 = tok_e[2 * b], e1 = tok_e[2 * b + 1];
    int r0 = off[e0] + tok_p[2 * b];
    int r1 = off[e1] + tok_p[2 * b + 1];
    float w0 = tok_w[2 * b], w1 = tok_w[2 * b + 1];
    int col = t * 4;
    f32x4 s0 = *(const f32x4*)(Y + (size_t)r0 * OO + col);
    f32x4 s1 = *(const f32x4*)(Y + (size_t)r1 * OO + col);
    f32x4 o = s0 * w0 + s1 * w1;
    *(f32x4*)(out + (size_t)b * OO + col) = o;
}

extern "C" void kernel_launch(void* const* d_in, const int* in_sizes, int n_in,
                              void* d_out, int out_size, void* d_ws, size_t ws_size,
                              hipStream_t stream)
{
    (void)in_sizes; (void)n_in; (void)out_size; (void)ws_size;
    const float* x  = (const float*)d_in[0];
    const float* Wr = (const float*)d_in[1];
    const float* br = (const float*)d_in[2];
    const float* W1 = (const float*)d_in[3];
    const float* b1 = (const float*)d_in[4];
    const float* W2 = (const float*)d_in[5];
    const float* b2 = (const float*)d_in[6];
    const float* W3 = (const float*)d_in[7];
    const float* b3 = (const float*)d_in[8];
    float* out = (float*)d_out;

    char* ws = (char*)d_ws;
    int*    counts = (int*)(ws + 0);
    int*    off    = (int*)(ws + 256);
    int*    tok_e  = (int*)(ws + 1024);
    int*    tok_p  = (int*)(ws + 9216);
    float*  tok_w  = (float*)(ws + 17408);
    int*    elist  = (int*)(ws + 25600);
    __bf16* Xg     = (__bf16*)(ws + 65536);
    __bf16* H1     = (__bf16*)(ws + 6356992);
    __bf16* H2     = (__bf16*)(ws + 18939904);
    float*  Y      = (float*)(ws + 31522816);

    hipMemsetAsync(counts, 0, 256, stream);
    router_kernel<<<1024, 256, 0, stream>>>(x, Wr, br, counts, elist, tok_e, tok_p, tok_w);
    offsets_kernel<<<1, 64, 0, stream>>>(counts, off);
    gather_kernel<<<dim3(32, 8), 256, 0, stream>>>(x, counts, off, elist, Xg);

    gemm_fused<1024, 2048, true,  true ><<<dim3(256, 8), 256, 0, stream>>>(Xg, W1, b1, (void*)H1, counts, off);
    gemm_fused<2048, 2048, true,  true ><<<dim3(256, 8), 256, 0, stream>>>(H1, W2, b2, (void*)H2, counts, off);
    gemm_fused<2048, 1024, false, false><<<dim3(128, 8), 256, 0, stream>>>(H2, W3, b3, (void*)Y,  counts, off);

    combine_kernel<<<1024, 256, 0, stream>>>(Y, off, tok_e, tok_p, tok_w, out);
}